// Round 8
// baseline (67.460 us; speedup 1.0000x reference)
//
#include <hip/hip_runtime.h>
#include <cfloat>
#include <cmath>

#define F_   8
#define H_   24
#define W_   24
#define NTOK 4608
#define NSEQ 4609
#define MPAD 4736           // 37*128 = 74*64
#define DIM  512
#define QKVC 1536           // q | k | v
#define NNB  28
#define NU   37             // union rows: BOS + 3*3*4
#define SCALEF 0.125f

typedef unsigned short ushort_t;
typedef __attribute__((ext_vector_type(8))) short short8v;
typedef __attribute__((ext_vector_type(8))) unsigned short ushort8v;
typedef __attribute__((ext_vector_type(4))) float floatx4;

typedef const __attribute__((address_space(1))) unsigned int guint_t;
typedef __attribute__((address_space(3))) unsigned int luint_t;

__device__ __forceinline__ float bf2f(unsigned short u) {
    return __uint_as_float(((unsigned)u) << 16);
}
__device__ __forceinline__ unsigned short f2bf(float f) {
    unsigned u = __float_as_uint(f);
    unsigned r = (u + 0x7FFFu + ((u >> 16) & 1u)) >> 16;
    return (unsigned short)r;
}

// ---------------------------------------------------------------------------
// Fused conversion (round-6 known-good):
//  blocks [0, XBLK):        x(f32) -> xb(bf16), rows zero-padded to MPAD
//  blocks [XBLK, XBLK+192): [w_q | w_kv] -> wcatT (bf16, [1536][512])
//  blocks [XBLK+192, +64):  w_out -> woutT (bf16, [512][512])
// ---------------------------------------------------------------------------
#define XBLK 1184                      // MPAD*512/2048
#define CONV_BLOCKS (XBLK + 192 + 64)

__global__ __launch_bounds__(256) void conv_k(
    const float* __restrict__ x, const float* __restrict__ wq,
    const float* __restrict__ wkv, const float* __restrict__ wout,
    ushort_t* __restrict__ xb, ushort_t* __restrict__ wcatT,
    ushort_t* __restrict__ woutT)
{
    const int bid = blockIdx.x, tid = threadIdx.x;
    __shared__ ushort_t tile[64][72];

    if (bid < XBLK) {
        int e0 = (bid * 256 + tid) * 8;
        int row = e0 >> 9;
        float4 a = make_float4(0.f, 0.f, 0.f, 0.f);
        float4 b = make_float4(0.f, 0.f, 0.f, 0.f);
        if (row < NSEQ) {
            a = *reinterpret_cast<const float4*>(&x[e0]);
            b = *reinterpret_cast<const float4*>(&x[e0 + 4]);
        }
        ushort8v o;
        o[0] = f2bf(a.x); o[1] = f2bf(a.y); o[2] = f2bf(a.z); o[3] = f2bf(a.w);
        o[4] = f2bf(b.x); o[5] = f2bf(b.y); o[6] = f2bf(b.z); o[7] = f2bf(b.w);
        *reinterpret_cast<ushort8v*>(&xb[e0]) = o;
        return;
    }

    int blk2 = bid - XBLK;
    const float* src; int ld, cb; ushort_t* dst; int k0;
    if (blk2 < 192) {
        int nt = blk2 >> 3, kt = blk2 & 7;
        int n0 = nt * 64;
        if (n0 < 512) { src = wq;  ld = 512;  cb = n0; }
        else          { src = wkv; ld = 1024; cb = n0 - 512; }
        dst = wcatT + (size_t)n0 * 512;
        k0 = kt * 64;
    } else {
        int b3 = blk2 - 192;
        int nt = b3 >> 3, kt = b3 & 7;
        src = wout; ld = 512; cb = nt * 64;
        dst = woutT + (size_t)(nt * 64) * 512;
        k0 = kt * 64;
    }

    {
        int r = tid >> 4, c4 = (tid & 15) * 4;
        #pragma unroll
        for (int p = 0; p < 4; ++p) {
            int rr = r + p * 16;
            float4 v = *reinterpret_cast<const float4*>(&src[(size_t)(k0 + rr) * ld + cb + c4]);
            tile[c4 + 0][rr] = f2bf(v.x);
            tile[c4 + 1][rr] = f2bf(v.y);
            tile[c4 + 2][rr] = f2bf(v.z);
            tile[c4 + 3][rr] = f2bf(v.w);
        }
    }
    __syncthreads();
    {
        int nl = tid >> 3, ks = (tid & 7) * 8;
        #pragma unroll
        for (int rep = 0; rep < 2; ++rep) {
            int nn = nl + rep * 32;
            ushort8v vv = *reinterpret_cast<const ushort8v*>(&tile[nn][ks]);
            *reinterpret_cast<ushort8v*>(&dst[(size_t)nn * 512 + k0 + ks]) = vv;
        }
    }
}

// ---------------------------------------------------------------------------
// bf16 MFMA GEMM (round-6 known-good): single-buffered, BM x 128 tile,
// BK=64, 4 waves, 16x16x32 MFMA, global_load_lds width-16, XOR slot swizzle,
// bijective XCD-chunked block swizzle, __launch_bounds__(256,4).
// ---------------------------------------------------------------------------
template<int BM, bool F32OUT>
__global__ __launch_bounds__(256, 4) void gemm_k(
    const ushort_t* __restrict__ A,    // [MPAD][512] bf16
    const ushort_t* __restrict__ BT,   // [N][512] bf16
    const float* __restrict__ bias,
    void* __restrict__ Cv, int ldc)
{
    __shared__ ushort_t sA[BM * 64];
    __shared__ ushort_t sB[128 * 64];
    const int tid = threadIdx.x;

    const int nwg = gridDim.x * gridDim.y;
    const int orig = blockIdx.y * gridDim.x + blockIdx.x;
    const int xcd = orig & 7;
    const int qq = nwg >> 3, rr8 = nwg & 7;
    const int wg = (xcd < rr8 ? xcd * (qq + 1) : rr8 * (qq + 1) + (xcd - rr8) * qq)
                   + (orig >> 3);
    const int row0 = (wg / gridDim.x) * BM;
    const int col0 = (wg % gridDim.x) * 128;

    const int wid = tid >> 6, lane = tid & 63;
    const int wr = wid >> 1, wc = wid & 1;
    const int l15 = lane & 15, kp = lane >> 4;
    constexpr int MR = BM / 32;        // m-fragments per wave

    floatx4 acc[MR][4];
    #pragma unroll
    for (int m = 0; m < MR; ++m)
        #pragma unroll
        for (int n = 0; n < 4; ++n)
            acc[m][n] = (floatx4){0.f, 0.f, 0.f, 0.f};

    const ushort_t* Abase = A + (size_t)row0 * 512;
    const ushort_t* Bbase = BT + (size_t)col0 * 512;

    for (int kt = 0; kt < 8; ++kt) {
        const int k0 = kt * 64;
        #pragma unroll
        for (int rnd = 0; rnd < BM / 32; ++rnd) {
            int r = rnd * 32 + (tid >> 3);
            int gs = (tid & 7) ^ (r & 7);
            __builtin_amdgcn_global_load_lds(
                (guint_t*)(Abase + (size_t)r * 512 + k0 + gs * 8),
                (luint_t*)(sA + r * 64 + (tid & 7) * 8), 16, 0, 0);
        }
        #pragma unroll
        for (int rnd = 0; rnd < 4; ++rnd) {
            int r = rnd * 32 + (tid >> 3);
            int gs = (tid & 7) ^ (r & 7);
            __builtin_amdgcn_global_load_lds(
                (guint_t*)(Bbase + (size_t)r * 512 + k0 + gs * 8),
                (luint_t*)(sB + r * 64 + (tid & 7) * 8), 16, 0, 0);
        }
        __syncthreads();

        #pragma unroll
        for (int kk = 0; kk < 2; ++kk) {
            short8v af[MR], bfr[4];
            #pragma unroll
            for (int m = 0; m < MR; ++m) {
                int r = wr * (BM / 2) + m * 16 + l15;
                int slot = kk * 4 + kp;
                af[m] = *(const short8v*)&sA[r * 64 + ((slot ^ (r & 7)) << 3)];
            }
            #pragma unroll
            for (int n = 0; n < 4; ++n) {
                int r = wc * 64 + n * 16 + l15;
                int slot = kk * 4 + kp;
                bfr[n] = *(const short8v*)&sB[r * 64 + ((slot ^ (r & 7)) << 3)];
            }
            #pragma unroll
            for (int m = 0; m < MR; ++m)
                #pragma unroll
                for (int n = 0; n < 4; ++n)
                    acc[m][n] = __builtin_amdgcn_mfma_f32_16x16x32_bf16(
                        af[m], bfr[n], acc[m][n], 0, 0, 0);
        }
        __syncthreads();
    }

    if (!F32OUT) {
        ushort_t* C = (ushort_t*)Cv;
        #pragma unroll
        for (int m = 0; m < MR; ++m) {
            int rb = row0 + wr * (BM / 2) + m * 16 + kp * 4;
            #pragma unroll
            for (int n = 0; n < 4; ++n) {
                int col = col0 + wc * 64 + n * 16 + l15;
                #pragma unroll
                for (int q = 0; q < 4; ++q)
                    C[(size_t)(rb + q) * ldc + col] = f2bf(acc[m][n][q]);
            }
        }
    } else {
        float* C = (float*)Cv;
        #pragma unroll
        for (int m = 0; m < MR; ++m) {
            int rb = row0 + wr * (BM / 2) + m * 16 + kp * 4;
            #pragma unroll
            for (int n = 0; n < 4; ++n) {
                int col = col0 + wc * 64 + n * 16 + l15;
                float bv = bias[col];
                #pragma unroll
                for (int q = 0; q < 4; ++q)
                    if (rb + q < NSEQ)
                        C[(size_t)(rb + q) * ldc + col] = acc[m][n][q] + bv;
            }
        }
    }
}

// ---------------------------------------------------------------------------
// Attention, TWO tokens per wave: A=(t,y,x even), B=(t,y,x+1).
// Union neighborhood = BOS + 3*3*4 offsets (dx rel A in [-1..2]) = 37 rows,
// vs 2*28 = 56 for separate waves. Shared rows loaded+converted once, feed
// both tokens' dot chains. All loads unbranched (batched, MLP preserved).
// Per-token masks via per-lane scalars + __shfl (no dynamic array indexing).
// ---------------------------------------------------------------------------
__global__ __launch_bounds__(256) void attn_k(
    const ushort_t* __restrict__ qkv,
    const float* __restrict__ wtalk,
    ushort_t* __restrict__ outh)
{
    const int lane = threadIdx.x & 63;
    const int bid0 = blockIdx.x;                            // 576 = 8*72
    const int bswz = (bid0 & 7) * (gridDim.x >> 3) + (bid0 >> 3);
    const int wj = bswz * 4 + (threadIdx.x >> 6);           // [0, 2304)
    const int iA = wj * 2, iB = iA + 1;
    const int h = lane >> 3, s = lane & 7;

    const int t = iA / (H_ * W_), rem = iA % (H_ * W_);
    const int yy = rem / W_, xA = rem % W_;                 // xA even, xA+1 < W_

    // per-lane union-row table (lane u in [0,37)): row id +1, 0 if OOB/BOS
    int rowu_ln = 0;
    if (lane >= 1 && lane < NU) {
        int e = lane - 1;
        int dt = e / 12 - 1, dy = (e % 12) / 4 - 1, dx = (e & 3) - 1;  // dx rel A
        int nt = t + dt, ny = yy + dy, nx = xA + dx;
        bool valid = ((unsigned)nt < (unsigned)F_) && ((unsigned)ny < (unsigned)H_) &&
                     ((unsigned)nx < (unsigned)W_);
        rowu_ln = valid ? ((nt * H_ + ny) * W_ + nx + 1) : 0;
    }
    // per-lane masked-row tables rel A and rel B (lane j in [0,28)): -1 masked
    int rowjA_ln = -1, rowjB_ln = -1;
    if (lane == 0) { rowjA_ln = 0; rowjB_ln = 0; }
    else if (lane < NNB) {
        int e = lane - 1;
        int dt = e / 9 - 1, dy = (e / 3) % 3 - 1, dx = e % 3 - 1;
        {
            int nt = t + dt, ny = yy + dy, nx = xA + dx;
            bool valid = ((unsigned)nt < (unsigned)F_) && ((unsigned)ny < (unsigned)H_) &&
                         ((unsigned)nx < (unsigned)W_);
            int u = (nt * H_ + ny) * W_ + nx;
            rowjA_ln = (valid && u <= iA) ? (u + 1) : -1;
        }
        {
            int nt = t + dt, ny = yy + dy, nx = xA + 1 + dx;
            bool valid = ((unsigned)nt < (unsigned)F_) && ((unsigned)ny < (unsigned)H_) &&
                         ((unsigned)nx < (unsigned)W_);
            int u = (nt * H_ + ny) * W_ + nx;
            rowjB_ln = (valid && u <= iB) ? (u + 1) : -1;
        }
    }

    // q fragments for both tokens
    float qfA[8], qfB[8];
    {
        ushort8v qa = *(const ushort8v*)&qkv[(size_t)(iA + 1) * QKVC + lane * 8];
        ushort8v qb = *(const ushort8v*)&qkv[(size_t)(iB + 1) * QKVC + lane * 8];
        #pragma unroll
        for (int e = 0; e < 8; ++e) { qfA[e] = bf2f(qa[e]); qfB[e] = bf2f(qb[e]); }
    }

    // K union pass: 37 rows, partial dots for both tokens
    float psA[NNB], psB[NNB];
    #pragma unroll
    for (int j = 0; j < NNB; ++j) { psA[j] = 0.f; psB[j] = 0.f; }
    #pragma unroll
    for (int u = 0; u < NU; ++u) {
        int r = __shfl(rowu_ln, u, 64);
        ushort8v kv = *(const ushort8v*)&qkv[(size_t)r * QKVC + 512 + lane * 8];
        float kf[8];
        #pragma unroll
        for (int e = 0; e < 8; ++e) kf[e] = bf2f(kv[e]);
        if (u == 0) {
            float a = 0.f, b = 0.f;
            #pragma unroll
            for (int e = 0; e < 8; ++e) { a += qfA[e] * kf[e]; b += qfB[e] * kf[e]; }
            psA[0] = a; psB[0] = b;
        } else {
            const int e = u - 1;
            const int dtp = e / 12, dyp = (e % 12) / 4, dxq = e & 3;  // dxq = dxA+1
            if (dxq <= 2) {
                const int jA = 1 + dtp * 9 + dyp * 3 + dxq;
                float a = 0.f;
                #pragma unroll
                for (int ee = 0; ee < 8; ++ee) a += qfA[ee] * kf[ee];
                psA[jA] = a;
            }
            if (dxq >= 1) {
                const int jB = 1 + dtp * 9 + dyp * 3 + (dxq - 1);
                float b = 0.f;
                #pragma unroll
                for (int ee = 0; ee < 8; ++ee) b += qfB[ee] * kf[ee];
                psB[jB] = b;
            }
        }
    }

    // reduce-scatter + mask + softmax + talking-heads for one token
    float wtg[8];
    #pragma unroll
    for (int hh = 0; hh < 8; ++hh) wtg[hh] = wtalk[h * 8 + hh];

    auto finish = [&](float* ps, int rowj_ln, float* pk) {
        float v1[14];
        {
            bool hi = (s & 1) != 0;
            #pragma unroll
            for (int m = 0; m < 14; ++m) {
                float keep = hi ? ps[2 * m + 1] : ps[2 * m];
                float oth  = hi ? ps[2 * m]     : ps[2 * m + 1];
                v1[m] = keep + __shfl_xor(oth, 1, 64);
            }
        }
        float v2[8];
        {
            bool hi = (s & 2) != 0;
            #pragma unroll
            for (int m = 0; m < 7; ++m) {
                float keep = hi ? v1[2 * m + 1] : v1[2 * m];
                float oth  = hi ? v1[2 * m]     : v1[2 * m + 1];
                v2[m] = keep + __shfl_xor(oth, 2, 64);
            }
            v2[7] = 0.f;
        }
        float simk[4];
        {
            bool hi = (s & 4) != 0;
            #pragma unroll
            for (int k = 0; k < 4; ++k) {
                float keep = hi ? v2[2 * k + 1] : v2[2 * k];
                float oth  = hi ? v2[2 * k]     : v2[2 * k + 1];
                simk[k] = keep + __shfl_xor(oth, 4, 64);
            }
        }
        #pragma unroll
        for (int k = 0; k < 4; ++k) {
            int j = s + 8 * k;
            int rj = __shfl(rowj_ln, j, 64);
            simk[k] = (rj >= 0) ? simk[k] * SCALEF : -FLT_MAX;
        }
        float mx = fmaxf(fmaxf(simk[0], simk[1]), fmaxf(simk[2], simk[3]));
        mx = fmaxf(mx, __shfl_xor(mx, 1, 64));
        mx = fmaxf(mx, __shfl_xor(mx, 2, 64));
        mx = fmaxf(mx, __shfl_xor(mx, 4, 64));
        float att[4];
        float S = 0.f;
        #pragma unroll
        for (int k = 0; k < 4; ++k) { att[k] = __expf(simk[k] - mx); S += att[k]; }
        S += __shfl_xor(S, 1, 64);
        S += __shfl_xor(S, 2, 64);
        S += __shfl_xor(S, 4, 64);
        float inv = 1.f / S;
        #pragma unroll
        for (int k = 0; k < 4; ++k) att[k] *= inv;
        #pragma unroll
        for (int k = 0; k < 4; ++k) {
            float acc = 0.f;
            #pragma unroll
            for (int hh = 0; hh < 8; ++hh)
                acc += wtg[hh] * __shfl(att[k], hh * 8 + s, 64);
            pk[k] = acc;
        }
    };

    float pkA[4], pkB[4];
    finish(psA, rowjA_ln, pkA);
    finish(psB, rowjB_ln, pkB);

    // PV union pass: 37 V rows, accumulate both outputs
    float oA[8], oB[8];
    #pragma unroll
    for (int e = 0; e < 8; ++e) { oA[e] = 0.f; oB[e] = 0.f; }
    #pragma unroll
    for (int u = 0; u < NU; ++u) {
        int r = __shfl(rowu_ln, u, 64);
        ushort8v vv = *(const ushort8v*)&qkv[(size_t)r * QKVC + 1024 + lane * 8];
        float vf[8];
        #pragma unroll
        for (int e = 0; e < 8; ++e) vf[e] = bf2f(vv[e]);
        if (u == 0) {
            float pa = __shfl(pkA[0], h * 8, 64);
            float pb = __shfl(pkB[0], h * 8, 64);
            #pragma unroll
            for (int e = 0; e < 8; ++e) { oA[e] += pa * vf[e]; oB[e] += pb * vf[e]; }
        } else {
            const int e = u - 1;
            const int dtp = e / 12, dyp = (e % 12) / 4, dxq = e & 3;
            if (dxq <= 2) {
                const int jA = 1 + dtp * 9 + dyp * 3 + dxq;
                float pa = __shfl(pkA[jA >> 3], h * 8 + (jA & 7), 64);
                #pragma unroll
                for (int ee = 0; ee < 8; ++ee) oA[ee] += pa * vf[ee];
            }
            if (dxq >= 1) {
                const int jB = 1 + dtp * 9 + dyp * 3 + (dxq - 1);
                float pb = __shfl(pkB[jB >> 3], h * 8 + (jB & 7), 64);
                #pragma unroll
                for (int ee = 0; ee < 8; ++ee) oB[ee] += pb * vf[ee];
            }
        }
    }

    ushort8v ovA, ovB;
    #pragma unroll
    for (int e = 0; e < 8; ++e) { ovA[e] = f2bf(oA[e]); ovB[e] = f2bf(oB[e]); }
    *(ushort8v*)&outh[(size_t)(iA + 1) * DIM + lane * 8] = ovA;
    *(ushort8v*)&outh[(size_t)(iB + 1) * DIM + lane * 8] = ovB;

    if (iA == 0) {
        ushort8v bv = *(const ushort8v*)&qkv[1024 + lane * 8];
        *(ushort8v*)&outh[lane * 8] = bv;
    }
}

extern "C" void kernel_launch(void* const* d_in, const int* in_sizes, int n_in,
                              void* d_out, int out_size, void* d_ws, size_t ws_size,
                              hipStream_t stream) {
    const float* x     = (const float*)d_in[0];
    const float* wq    = (const float*)d_in[1];
    const float* wkv   = (const float*)d_in[2];
    const float* wtalk = (const float*)d_in[3];
    const float* wout  = (const float*)d_in[4];
    const float* bout  = (const float*)d_in[5];
    float* out = (float*)d_out;

    ushort_t* xb    = (ushort_t*)d_ws;                    // MPAD*512 bf16
    ushort_t* wcatT = xb    + (size_t)MPAD * 512;         // 1536*512
    ushort_t* woutT = wcatT + (size_t)QKVC * 512;         // 512*512
    ushort_t* qkv   = woutT + (size_t)512 * 512;          // MPAD*1536
    ushort_t* outh  = qkv   + (size_t)MPAD * QKVC;        // MPAD*512

    dim3 blk(256);
    conv_k<<<CONV_BLOCKS, blk, 0, stream>>>(x, wq, wkv, wout, xb, wcatT, woutT);
    gemm_k<64, false><<<dim3(12, 74), blk, 0, stream>>>(xb, wcatT, nullptr, qkv, QKVC);
    attn_k<<<dim3(NTOK / 8), blk, 0, stream>>>(qkv, wtalk, outh);
    gemm_k<64, true><<<dim3(4, 74), blk, 0, stream>>>(outh, woutT, bout, out, DIM);
}

// Round 9
// 48.378 us; speedup vs baseline: 1.3944x; 1.3944x over previous
//
#include <hip/hip_runtime.h>
#include <cfloat>
#include <cmath>

#define F_   8
#define H_   24
#define W_   24
#define NTOK 4608
#define NSEQ 4609
#define MPAD 4736           // 37*128 = 74*64
#define DIM  512
#define QKVC 1536           // q | k | v
#define NNB  28
#define SCALEF 0.125f

typedef unsigned short ushort_t;
typedef __attribute__((ext_vector_type(8))) short short8v;
typedef __attribute__((ext_vector_type(8))) unsigned short ushort8v;
typedef __attribute__((ext_vector_type(4))) float floatx4;

typedef const __attribute__((address_space(1))) unsigned int guint_t;
typedef __attribute__((address_space(3))) unsigned int luint_t;

__device__ __forceinline__ float bf2f(unsigned short u) {
    return __uint_as_float(((unsigned)u) << 16);
}
__device__ __forceinline__ unsigned short f2bf(float f) {
    unsigned u = __float_as_uint(f);
    unsigned r = (u + 0x7FFFu + ((u >> 16) & 1u)) >> 16;
    return (unsigned short)r;
}

// ---------------------------------------------------------------------------
// Fused conversion (round-6 known-good):
//  blocks [0, XBLK):        x(f32) -> xb(bf16), rows zero-padded to MPAD
//  blocks [XBLK, XBLK+192): [w_q | w_kv] -> wcatT (bf16, [1536][512])
//  blocks [XBLK+192, +64):  w_out -> woutT (bf16, [512][512])
// ---------------------------------------------------------------------------
#define XBLK 1184                      // MPAD*512/2048
#define CONV_BLOCKS (XBLK + 192 + 64)

__global__ __launch_bounds__(256) void conv_k(
    const float* __restrict__ x, const float* __restrict__ wq,
    const float* __restrict__ wkv, const float* __restrict__ wout,
    ushort_t* __restrict__ xb, ushort_t* __restrict__ wcatT,
    ushort_t* __restrict__ woutT)
{
    const int bid = blockIdx.x, tid = threadIdx.x;
    __shared__ ushort_t tile[64][72];

    if (bid < XBLK) {
        int e0 = (bid * 256 + tid) * 8;
        int row = e0 >> 9;
        float4 a = make_float4(0.f, 0.f, 0.f, 0.f);
        float4 b = make_float4(0.f, 0.f, 0.f, 0.f);
        if (row < NSEQ) {
            a = *reinterpret_cast<const float4*>(&x[e0]);
            b = *reinterpret_cast<const float4*>(&x[e0 + 4]);
        }
        ushort8v o;
        o[0] = f2bf(a.x); o[1] = f2bf(a.y); o[2] = f2bf(a.z); o[3] = f2bf(a.w);
        o[4] = f2bf(b.x); o[5] = f2bf(b.y); o[6] = f2bf(b.z); o[7] = f2bf(b.w);
        *reinterpret_cast<ushort8v*>(&xb[e0]) = o;
        return;
    }

    int blk2 = bid - XBLK;
    const float* src; int ld, cb; ushort_t* dst; int k0;
    if (blk2 < 192) {
        int nt = blk2 >> 3, kt = blk2 & 7;
        int n0 = nt * 64;
        if (n0 < 512) { src = wq;  ld = 512;  cb = n0; }
        else          { src = wkv; ld = 1024; cb = n0 - 512; }
        dst = wcatT + (size_t)n0 * 512;
        k0 = kt * 64;
    } else {
        int b3 = blk2 - 192;
        int nt = b3 >> 3, kt = b3 & 7;
        src = wout; ld = 512; cb = nt * 64;
        dst = woutT + (size_t)(nt * 64) * 512;
        k0 = kt * 64;
    }

    {
        int r = tid >> 4, c4 = (tid & 15) * 4;
        #pragma unroll
        for (int p = 0; p < 4; ++p) {
            int rr = r + p * 16;
            float4 v = *reinterpret_cast<const float4*>(&src[(size_t)(k0 + rr) * ld + cb + c4]);
            tile[c4 + 0][rr] = f2bf(v.x);
            tile[c4 + 1][rr] = f2bf(v.y);
            tile[c4 + 2][rr] = f2bf(v.z);
            tile[c4 + 3][rr] = f2bf(v.w);
        }
    }
    __syncthreads();
    {
        int nl = tid >> 3, ks = (tid & 7) * 8;
        #pragma unroll
        for (int rep = 0; rep < 2; ++rep) {
            int nn = nl + rep * 32;
            ushort8v vv = *reinterpret_cast<const ushort8v*>(&tile[nn][ks]);
            *reinterpret_cast<ushort8v*>(&dst[(size_t)nn * 512 + k0 + ks]) = vv;
        }
    }
}

// ---------------------------------------------------------------------------
// bf16 MFMA GEMM (round-6 known-good): single-buffered, BM x 128 tile,
// BK=64, 4 waves, 16x16x32 MFMA, global_load_lds width-16, XOR slot swizzle,
// bijective XCD-chunked block swizzle, __launch_bounds__(256,4).
// ---------------------------------------------------------------------------
template<int BM, bool F32OUT>
__global__ __launch_bounds__(256, 4) void gemm_k(
    const ushort_t* __restrict__ A,    // [MPAD][512] bf16
    const ushort_t* __restrict__ BT,   // [N][512] bf16
    const float* __restrict__ bias,
    void* __restrict__ Cv, int ldc)
{
    __shared__ ushort_t sA[BM * 64];
    __shared__ ushort_t sB[128 * 64];
    const int tid = threadIdx.x;

    const int nwg = gridDim.x * gridDim.y;
    const int orig = blockIdx.y * gridDim.x + blockIdx.x;
    const int xcd = orig & 7;
    const int qq = nwg >> 3, rr8 = nwg & 7;
    const int wg = (xcd < rr8 ? xcd * (qq + 1) : rr8 * (qq + 1) + (xcd - rr8) * qq)
                   + (orig >> 3);
    const int row0 = (wg / gridDim.x) * BM;
    const int col0 = (wg % gridDim.x) * 128;

    const int wid = tid >> 6, lane = tid & 63;
    const int wr = wid >> 1, wc = wid & 1;
    const int l15 = lane & 15, kp = lane >> 4;
    constexpr int MR = BM / 32;        // m-fragments per wave

    floatx4 acc[MR][4];
    #pragma unroll
    for (int m = 0; m < MR; ++m)
        #pragma unroll
        for (int n = 0; n < 4; ++n)
            acc[m][n] = (floatx4){0.f, 0.f, 0.f, 0.f};

    const ushort_t* Abase = A + (size_t)row0 * 512;
    const ushort_t* Bbase = BT + (size_t)col0 * 512;

    for (int kt = 0; kt < 8; ++kt) {
        const int k0 = kt * 64;
        #pragma unroll
        for (int rnd = 0; rnd < BM / 32; ++rnd) {
            int r = rnd * 32 + (tid >> 3);
            int gs = (tid & 7) ^ (r & 7);
            __builtin_amdgcn_global_load_lds(
                (guint_t*)(Abase + (size_t)r * 512 + k0 + gs * 8),
                (luint_t*)(sA + r * 64 + (tid & 7) * 8), 16, 0, 0);
        }
        #pragma unroll
        for (int rnd = 0; rnd < 4; ++rnd) {
            int r = rnd * 32 + (tid >> 3);
            int gs = (tid & 7) ^ (r & 7);
            __builtin_amdgcn_global_load_lds(
                (guint_t*)(Bbase + (size_t)r * 512 + k0 + gs * 8),
                (luint_t*)(sB + r * 64 + (tid & 7) * 8), 16, 0, 0);
        }
        __syncthreads();

        #pragma unroll
        for (int kk = 0; kk < 2; ++kk) {
            short8v af[MR], bfr[4];
            #pragma unroll
            for (int m = 0; m < MR; ++m) {
                int r = wr * (BM / 2) + m * 16 + l15;
                int slot = kk * 4 + kp;
                af[m] = *(const short8v*)&sA[r * 64 + ((slot ^ (r & 7)) << 3)];
            }
            #pragma unroll
            for (int n = 0; n < 4; ++n) {
                int r = wc * 64 + n * 16 + l15;
                int slot = kk * 4 + kp;
                bfr[n] = *(const short8v*)&sB[r * 64 + ((slot ^ (r & 7)) << 3)];
            }
            #pragma unroll
            for (int m = 0; m < MR; ++m)
                #pragma unroll
                for (int n = 0; n < 4; ++n)
                    acc[m][n] = __builtin_amdgcn_mfma_f32_16x16x32_bf16(
                        af[m], bfr[n], acc[m][n], 0, 0, 0);
        }
        __syncthreads();
    }

    if (!F32OUT) {
        ushort_t* C = (ushort_t*)Cv;
        #pragma unroll
        for (int m = 0; m < MR; ++m) {
            int rb = row0 + wr * (BM / 2) + m * 16 + kp * 4;
            #pragma unroll
            for (int n = 0; n < 4; ++n) {
                int col = col0 + wc * 64 + n * 16 + l15;
                #pragma unroll
                for (int q = 0; q < 4; ++q)
                    C[(size_t)(rb + q) * ldc + col] = f2bf(acc[m][n][q]);
            }
        }
    } else {
        float* C = (float*)Cv;
        #pragma unroll
        for (int m = 0; m < MR; ++m) {
            int rb = row0 + wr * (BM / 2) + m * 16 + kp * 4;
            #pragma unroll
            for (int n = 0; n < 4; ++n) {
                int col = col0 + wc * 64 + n * 16 + l15;
                float bv = bias[col];
                #pragma unroll
                for (int q = 0; q < 4; ++q)
                    if (rb + q < NSEQ)
                        C[(size_t)(rb + q) * ldc + col] = acc[m][n][q] + bv;
            }
        }
    }
}

// ---------------------------------------------------------------------------
// Attention, wave-per-token (round-6 layout), latency-optimized:
//  - __launch_bounds__(256,4): 128-VGPR budget (grid caps occupancy at
//    ~4.5 waves/SIMD anyway, so extra registers are free)
//  - K rows loaded in explicit chunks of 12 into named register arrays ->
//    ~12 loads in flight instead of the compiler's minimal-liveness few
//  - V chunk-1 (12 rows) prefetched BEFORE reduce/softmax/talking-heads;
//    its ~200-cycle L2 latency hides under ~600 cycles of shfl work
//  - PV shfl broadcasts hoisted (no shfl->load->fma serial chain)
// All loads unbranched (masked rows clamp to row 0, L1-hot).
// ---------------------------------------------------------------------------
__global__ __launch_bounds__(256, 4) void attn_k(
    const ushort_t* __restrict__ qkv,
    const float* __restrict__ wtalk,
    ushort_t* __restrict__ outh)
{
    const int lane = threadIdx.x & 63;
    const int bid0 = blockIdx.x;                            // 1152 = 8*144
    const int bswz = (bid0 & 7) * (gridDim.x >> 3) + (bid0 >> 3);
    const int i = bswz * 4 + (threadIdx.x >> 6);
    const int h = lane >> 3, s = lane & 7;

    const int t = i / (H_ * W_), rem = i % (H_ * W_);
    const int yy = rem / W_, xx = rem % W_;

    int rowj = -1;
    if (lane == 0) rowj = 0;
    else if (lane < NNB) {
        int e = lane - 1;
        int dt = e / 9 - 1, dy = (e / 3) % 3 - 1, dx = e % 3 - 1;
        int nt = t + dt, ny = yy + dy, nx = xx + dx;
        bool valid = ((unsigned)nt < (unsigned)F_) && ((unsigned)ny < (unsigned)H_) &&
                     ((unsigned)nx < (unsigned)W_);
        int u = (nt * H_ + ny) * W_ + nx;
        rowj = (valid && u <= i) ? (u + 1) : -1;
    }

    // clamped row table for loads (masked -> row 0)
    int rows[NNB];
    #pragma unroll
    for (int j = 0; j < NNB; ++j) {
        int r = __shfl(rowj, j, 64);
        rows[j] = r < 0 ? 0 : r;
    }

    float qf[8];
    {
        ushort8v qv = *(const ushort8v*)&qkv[(size_t)(i + 1) * QKVC + lane * 8];
        #pragma unroll
        for (int e = 0; e < 8; ++e) qf[e] = bf2f(qv[e]);
    }

    // ---- K dots, chunked 12/12/4 (batched loads per chunk) ----
    float ps[NNB];
    {
        ushort8v kc[12];
        #pragma unroll
        for (int j = 0; j < 12; ++j)
            kc[j] = *(const ushort8v*)&qkv[(size_t)rows[j] * QKVC + 512 + lane * 8];
        #pragma unroll
        for (int j = 0; j < 12; ++j) {
            float a = 0.f;
            #pragma unroll
            for (int e = 0; e < 8; ++e) a += qf[e] * bf2f(kc[j][e]);
            ps[j] = a;
        }
        #pragma unroll
        for (int j = 12; j < 24; ++j)
            kc[j - 12] = *(const ushort8v*)&qkv[(size_t)rows[j] * QKVC + 512 + lane * 8];
        #pragma unroll
        for (int j = 12; j < 24; ++j) {
            float a = 0.f;
            #pragma unroll
            for (int e = 0; e < 8; ++e) a += qf[e] * bf2f(kc[j - 12][e]);
            ps[j] = a;
        }
        ushort8v kt_[4];
        #pragma unroll
        for (int j = 24; j < 28; ++j)
            kt_[j - 24] = *(const ushort8v*)&qkv[(size_t)rows[j] * QKVC + 512 + lane * 8];
        #pragma unroll
        for (int j = 24; j < 28; ++j) {
            float a = 0.f;
            #pragma unroll
            for (int e = 0; e < 8; ++e) a += qf[e] * bf2f(kt_[j - 24][e]);
            ps[j] = a;
        }
    }

    // ---- V chunk-1 prefetch: in flight across reduce/softmax/TH ----
    ushort8v vc[12];
    #pragma unroll
    for (int j = 0; j < 12; ++j)
        vc[j] = *(const ushort8v*)&qkv[(size_t)rows[j] * QKVC + 1024 + lane * 8];

    // ---- reduce-scatter (xor 1,2,4) ----
    float v1[14];
    {
        bool hi = (s & 1) != 0;
        #pragma unroll
        for (int m = 0; m < 14; ++m) {
            float keep = hi ? ps[2 * m + 1] : ps[2 * m];
            float oth  = hi ? ps[2 * m]     : ps[2 * m + 1];
            v1[m] = keep + __shfl_xor(oth, 1, 64);
        }
    }
    float v2[8];
    {
        bool hi = (s & 2) != 0;
        #pragma unroll
        for (int m = 0; m < 7; ++m) {
            float keep = hi ? v1[2 * m + 1] : v1[2 * m];
            float oth  = hi ? v1[2 * m]     : v1[2 * m + 1];
            v2[m] = keep + __shfl_xor(oth, 2, 64);
        }
        v2[7] = 0.f;
    }
    float simk[4];
    {
        bool hi = (s & 4) != 0;
        #pragma unroll
        for (int k = 0; k < 4; ++k) {
            float keep = hi ? v2[2 * k + 1] : v2[2 * k];
            float oth  = hi ? v2[2 * k]     : v2[2 * k + 1];
            simk[k] = keep + __shfl_xor(oth, 4, 64);
        }
    }
    #pragma unroll
    for (int k = 0; k < 4; ++k) {
        int j = s + 8 * k;
        int rj = __shfl(rowj, j, 64);
        simk[k] = (rj >= 0) ? simk[k] * SCALEF : -FLT_MAX;
    }

    // ---- softmax over the 8-lane x 4-slot group ----
    float mx = fmaxf(fmaxf(simk[0], simk[1]), fmaxf(simk[2], simk[3]));
    mx = fmaxf(mx, __shfl_xor(mx, 1, 64));
    mx = fmaxf(mx, __shfl_xor(mx, 2, 64));
    mx = fmaxf(mx, __shfl_xor(mx, 4, 64));
    float att[4];
    float S = 0.f;
    #pragma unroll
    for (int k = 0; k < 4; ++k) { att[k] = __expf(simk[k] - mx); S += att[k]; }
    S += __shfl_xor(S, 1, 64);
    S += __shfl_xor(S, 2, 64);
    S += __shfl_xor(S, 4, 64);
    float inv = 1.f / S;
    #pragma unroll
    for (int k = 0; k < 4; ++k) att[k] *= inv;

    // ---- talking heads ----
    float wtg[8];
    #pragma unroll
    for (int hh = 0; hh < 8; ++hh) wtg[hh] = wtalk[h * 8 + hh];
    float pk[4];
    #pragma unroll
    for (int k = 0; k < 4; ++k) {
        float acc = 0.f;
        #pragma unroll
        for (int hh = 0; hh < 8; ++hh)
            acc += wtg[hh] * __shfl(att[k], hh * 8 + s, 64);
        pk[k] = acc;
    }

    // hoisted PV broadcasts
    float pj[NNB];
    #pragma unroll
    for (int j = 0; j < NNB; ++j)
        pj[j] = __shfl(pk[j >> 3], h * 8 + (j & 7), 64);

    // ---- PV, chunked 12/12/4 ----
    float o[8];
    #pragma unroll
    for (int e = 0; e < 8; ++e) o[e] = 0.f;
    #pragma unroll
    for (int j = 0; j < 12; ++j) {
        #pragma unroll
        for (int e = 0; e < 8; ++e) o[e] += pj[j] * bf2f(vc[j][e]);
    }
    #pragma unroll
    for (int j = 12; j < 24; ++j)
        vc[j - 12] = *(const ushort8v*)&qkv[(size_t)rows[j] * QKVC + 1024 + lane * 8];
    #pragma unroll
    for (int j = 12; j < 24; ++j) {
        #pragma unroll
        for (int e = 0; e < 8; ++e) o[e] += pj[j] * bf2f(vc[j - 12][e]);
    }
    {
        ushort8v vt_[4];
        #pragma unroll
        for (int j = 24; j < 28; ++j)
            vt_[j - 24] = *(const ushort8v*)&qkv[(size_t)rows[j] * QKVC + 1024 + lane * 8];
        #pragma unroll
        for (int j = 24; j < 28; ++j) {
            #pragma unroll
            for (int e = 0; e < 8; ++e) o[e] += pj[j] * bf2f(vt_[j - 24][e]);
        }
    }

    ushort8v ov;
    #pragma unroll
    for (int e = 0; e < 8; ++e) ov[e] = f2bf(o[e]);
    *(ushort8v*)&outh[(size_t)(i + 1) * DIM + lane * 8] = ov;

    if (i == 0) {
        ushort8v bv = *(const ushort8v*)&qkv[1024 + lane * 8];
        *(ushort8v*)&outh[lane * 8] = bv;
    }
}

extern "C" void kernel_launch(void* const* d_in, const int* in_sizes, int n_in,
                              void* d_out, int out_size, void* d_ws, size_t ws_size,
                              hipStream_t stream) {
    const float* x     = (const float*)d_in[0];
    const float* wq    = (const float*)d_in[1];
    const float* wkv   = (const float*)d_in[2];
    const float* wtalk = (const float*)d_in[3];
    const float* wout  = (const float*)d_in[4];
    const float* bout  = (const float*)d_in[5];
    float* out = (float*)d_out;

    ushort_t* xb    = (ushort_t*)d_ws;                    // MPAD*512 bf16
    ushort_t* wcatT = xb    + (size_t)MPAD * 512;         // 1536*512
    ushort_t* woutT = wcatT + (size_t)QKVC * 512;         // 512*512
    ushort_t* qkv   = woutT + (size_t)512 * 512;          // MPAD*1536
    ushort_t* outh  = qkv   + (size_t)MPAD * QKVC;        // MPAD*512

    dim3 blk(256);
    conv_k<<<CONV_BLOCKS, blk, 0, stream>>>(x, wq, wkv, wout, xb, wcatT, woutT);
    gemm_k<64, false><<<dim3(12, 74), blk, 0, stream>>>(xb, wcatT, nullptr, qkv, QKVC);
    attn_k<<<dim3(NTOK / 4), blk, 0, stream>>>(qkv, wtalk, outh);
    gemm_k<64, true><<<dim3(4, 74), blk, 0, stream>>>(outh, woutT, bout, out, DIM);
}